// Round 3
// baseline (19.791 us; speedup 1.0000x reference)
//
#include <hip/hip_runtime.h>

typedef float v2f __attribute__((ext_vector_type(2)));

__device__ __forceinline__ v2f vfma(v2f a, v2f b, v2f c) {
    return __builtin_elementwise_fma(a, b, c);
}
__device__ __forceinline__ v2f splat(float x) { v2f r; r.x = x; r.y = x; return r; }

__device__ __forceinline__ float rcp_fast(float x) { return __builtin_amdgcn_rcpf(x); }

// tanh(x) = (1 - e^{-2x}) / (1 + e^{-2x}); all inputs here bounded |x| < ~6.
__device__ __forceinline__ float tanh_fast(float x) {
    float e = __expf(-2.0f * x);
    return (1.0f - e) * rcp_fast(1.0f + e);
}

__device__ __forceinline__ void cmul(float ar, float ai, float br, float bi,
                                     float& cr, float& ci) {
    cr = ar * br - ai * bi;
    ci = ar * bi + ai * br;
}

// Adjacent-lane (pair) exchange via DPP quad_perm [1,0,3,2] = 0xB1.
__device__ __forceinline__ float pswap(float v) {
    int i = __builtin_bit_cast(int, v);
    i = __builtin_amdgcn_mov_dpp(i, 0xB1, 0xF, 0xF, true);
    return __builtin_bit_cast(float, i);
}
__device__ __forceinline__ v2f pswap2(v2f v) {
    v2f r; r.x = pswap(v.x); r.y = pswap(v.y); return r;
}

// Local butterfly gates on 4 v2f regs (8 amps). K = v2f-index stride.
template<int K>
__device__ __forceinline__ void rx_local(v2f (&sr)[4], v2f (&si)[4], float s, float c) {
    v2f cs = splat(c), ss = splat(s);
    #pragma unroll
    for (int k = 0; k < 4; ++k) {
        if ((k & K) == 0) {
            const int e = k + K;
            v2f ar = sr[k], ai = si[k], br = sr[e], bi = si[e];
            sr[k] = vfma(cs, ar,  ss * bi);
            si[k] = vfma(cs, ai, -(ss * br));
            sr[e] = vfma(cs, br,  ss * ai);
            si[e] = vfma(cs, bi, -(ss * ar));
        }
    }
}
template<int K>
__device__ __forceinline__ void ry_local(v2f (&sr)[4], v2f (&si)[4], float s, float c) {
    v2f cs = splat(c), ss = splat(s);
    #pragma unroll
    for (int k = 0; k < 4; ++k) {
        if ((k & K) == 0) {
            const int e = k + K;
            v2f ar = sr[k], ai = si[k], br = sr[e], bi = si[e];
            sr[k] = vfma(cs, ar, -(ss * br));
            si[k] = vfma(cs, ai, -(ss * bi));
            sr[e] = vfma(ss, ar,  cs * br);
            si[e] = vfma(ss, ai,  cs * bi);
        }
    }
}
// Within-v2f gates (local stride 1) via .yx swizzle (op_sel).
__device__ __forceinline__ void rx_1(v2f (&sr)[4], v2f (&si)[4], float s, float c) {
    v2f cs = splat(c), ss = splat(s);
    #pragma unroll
    for (int k = 0; k < 4; ++k) {
        v2f r = sr[k], i = si[k];
        sr[k] = vfma(cs, r,  ss * i.yx);
        si[k] = vfma(cs, i, -(ss * r.yx));
    }
}
__device__ __forceinline__ void ry_1(v2f (&sr)[4], v2f (&si)[4], float s, float c) {
    v2f cs = splat(c);
    v2f sn; sn.x = -s; sn.y = s;
    #pragma unroll
    for (int k = 0; k < 4; ++k) {
        v2f r = sr[k], i = si[k];
        sr[k] = vfma(cs, r, sn * r.yx);
        si[k] = vfma(cs, i, sn * i.yx);
    }
}

__global__ void __launch_bounds__(256, 4)
qpinn_kernel(const float* __restrict__ xy,
             const float* __restrict__ W1, const float* __restrict__ b1,
             const float* __restrict__ W2, const float* __restrict__ b2,
             const float* __restrict__ W3, const float* __restrict__ b3,
             const float* __restrict__ W4, const float* __restrict__ b4,
             float* __restrict__ out, int B)
{
    // W2 (16,40) staged interleaved per column-pair:
    // w2s[((l*4+m2)*16 + k)*2 + c] = W2[k][l*8 + m2*2 + c]
    __shared__ __align__(16) float w2s[640];
    for (int i = threadIdx.x; i < 640; i += 256) {
        int c = i & 1, k = (i >> 1) & 15, m2 = (i >> 5) & 3, l = i >> 7;
        w2s[i] = W2[k * 40 + l * 8 + m2 * 2 + c];
    }
    __syncthreads();

    int tid = blockIdx.x * 256 + threadIdx.x;
    int t = tid >> 1;      // element index
    int p = tid & 1;       // qubit-0 bit held by this lane
    if (t >= B) return;

    const float psign = p ? 1.0f : -1.0f;

    float2 P = reinterpret_cast<const float2*>(xy)[t];
    float x = P.x, y = P.y;

    // ---- front MLP: this lane computes h_j for j = 8p..8p+7; partner half via DPP ----
    const int j0 = 8 * p;
    float4 w1xa = *(const float4*)(W1 + j0);
    float4 w1xb = *(const float4*)(W1 + j0 + 4);
    float4 w1ya = *(const float4*)(W1 + 16 + j0);
    float4 w1yb = *(const float4*)(W1 + 16 + j0 + 4);
    float4 b1a  = *(const float4*)(b1 + j0);
    float4 b1b  = *(const float4*)(b1 + j0 + 4);
    float hl[8], hq[8];
    hl[0] = tanh_fast(fmaf(x, w1xa.x, fmaf(y, w1ya.x, b1a.x)));
    hl[1] = tanh_fast(fmaf(x, w1xa.y, fmaf(y, w1ya.y, b1a.y)));
    hl[2] = tanh_fast(fmaf(x, w1xa.z, fmaf(y, w1ya.z, b1a.z)));
    hl[3] = tanh_fast(fmaf(x, w1xa.w, fmaf(y, w1ya.w, b1a.w)));
    hl[4] = tanh_fast(fmaf(x, w1xb.x, fmaf(y, w1yb.x, b1b.x)));
    hl[5] = tanh_fast(fmaf(x, w1xb.y, fmaf(y, w1yb.y, b1b.y)));
    hl[6] = tanh_fast(fmaf(x, w1xb.z, fmaf(y, w1yb.z, b1b.z)));
    hl[7] = tanh_fast(fmaf(x, w1xb.w, fmaf(y, w1yb.w, b1b.w)));
    #pragma unroll
    for (int jj = 0; jj < 8; ++jj) hq[jj] = pswap(hl[jj]);

    // ---- initial state (8 local amps, d = 8p + m) ----
    float sa = __builtin_amdgcn_sinf(0.25f * x), ca = __builtin_amdgcn_cosf(0.25f * x);
    float sb = __builtin_amdgcn_sinf(0.25f * y), cb = __builtin_amdgcn_cosf(0.25f * y);
    const float is2 = 0.70710678118654752f;
    float m0 = is2 * (ca - sa), m1 = is2 * (ca + sa);
    float u0r = m0 * cb, u0i = -m0 * sb;
    float u1r = m1 * cb, u1i =  m1 * sb;
    float a2r, a2i, bb2r, bb2i;
    cmul(u0r, u0i, u0r, u0i, a2r, a2i);         // u0^2
    cmul(u1r, u1i, u1r, u1i, bb2r, bb2i);       // u1^2
    float t0r, t0i, t1r, t1i, t2r, t2i, t3r, t3i;
    cmul(a2r, a2i, u0r, u0i, t0r, t0i);         // u0^3
    cmul(a2r, a2i, u1r, u1i, t1r, t1i);         // u0^2 u1
    cmul(bb2r, bb2i, u0r, u0i, t2r, t2i);       // u0 u1^2
    cmul(bb2r, bb2i, u1r, u1i, t3r, t3i);       // u1^3
    float wr = p ? u1r : u0r, wi = p ? u1i : u0i;
    // local m popcount3 = {0,1,1,2,1,2,2,3} -> v2f t-pairs per k
    v2f sr[4], si[4];
    {
        v2f pr[4] = {{t0r, t1r}, {t1r, t2r}, {t1r, t2r}, {t2r, t3r}};
        v2f pi[4] = {{t0i, t1i}, {t1i, t2i}, {t1i, t2i}, {t2i, t3i}};
        v2f wrv = splat(wr), wiv = splat(wi);
        #pragma unroll
        for (int k = 0; k < 4; ++k) {
            sr[k] = vfma(wrv, pr[k], -(wiv * pi[k]));
            si[k] = vfma(wrv, pi[k],  wiv * pr[k]);
        }
    }

    // CZ per-lane sign packs (states {3,6,9,12}): flips:
    // [0].y iff p==1, [1].y iff p==0, [2].x iff p==1, [3].x iff p==0
    v2f czA; czA.x = 1.0f; czA.y = -psign;
    v2f czB; czB.x = 1.0f; czB.y =  psign;
    v2f czC; czC.x = -psign; czC.y = 1.0f;
    v2f czD; czD.x =  psign; czD.y = 1.0f;

    const float REV = 0.5f * 0.15915494309189535f;  // (t/2) in revolutions

    // ---- layers ----
    #pragma unroll
    for (int l = 0; l < 5; ++l) {
        // angle dots: this lane's 4 columns j = l*8 + 4p + {0..3} (2 v2f col-pairs)
        float4 b2v = *(const float4*)(b2 + l * 8 + 4 * p);
        v2f acc0; acc0.x = b2v.x; acc0.y = b2v.y;
        v2f acc1; acc1.x = b2v.z; acc1.y = b2v.w;
        const float* blk0 = w2s + (l * 4 + 2 * p) * 32;
        const float* blk1 = blk0 + 32;
        const int own = 16 * p, par = 16 - 16 * p;
        #pragma unroll
        for (int kk = 0; kk < 8; kk += 2) {
            float4 wA = *(const float4*)(blk0 + own + 2 * kk);
            float4 wB = *(const float4*)(blk1 + own + 2 * kk);
            v2f wAlo; wAlo.x = wA.x; wAlo.y = wA.y;
            v2f wAhi; wAhi.x = wA.z; wAhi.y = wA.w;
            v2f wBlo; wBlo.x = wB.x; wBlo.y = wB.y;
            v2f wBhi; wBhi.x = wB.z; wBhi.y = wB.w;
            acc0 = vfma(splat(hl[kk]),     wAlo, acc0);
            acc0 = vfma(splat(hl[kk + 1]), wAhi, acc0);
            acc1 = vfma(splat(hl[kk]),     wBlo, acc1);
            acc1 = vfma(splat(hl[kk + 1]), wBhi, acc1);
        }
        #pragma unroll
        for (int kk = 0; kk < 8; kk += 2) {
            float4 wA = *(const float4*)(blk0 + par + 2 * kk);
            float4 wB = *(const float4*)(blk1 + par + 2 * kk);
            v2f wAlo; wAlo.x = wA.x; wAlo.y = wA.y;
            v2f wAhi; wAhi.x = wA.z; wAhi.y = wA.w;
            v2f wBlo; wBlo.x = wB.x; wBlo.y = wB.y;
            v2f wBhi; wBhi.x = wB.z; wBhi.y = wB.w;
            acc0 = vfma(splat(hq[kk]),     wAlo, acc0);
            acc0 = vfma(splat(hq[kk + 1]), wAhi, acc0);
            acc1 = vfma(splat(hq[kk]),     wBlo, acc1);
            acc1 = vfma(splat(hq[kk + 1]), wBhi, acc1);
        }
        float aown[4];
        aown[0] = tanh_fast(acc0.x);
        aown[1] = tanh_fast(acc0.y);
        aown[2] = tanh_fast(acc1.x);
        aown[3] = tanh_fast(acc1.y);
        float apar[4];
        #pragma unroll
        for (int w = 0; w < 4; ++w) apar[w] = pswap(aown[w]);
        // full 8 angles: RX (m=0..3) and RY (m=4..7)
        float sx[4], cx[4], sy[4], cy[4];
        #pragma unroll
        for (int w = 0; w < 4; ++w) {
            float arx = p ? apar[w] : aown[w];
            float ary = p ? aown[w] : apar[w];
            float r1 = arx * REV, r2 = ary * REV;
            sx[w] = __builtin_amdgcn_sinf(r1); cx[w] = __builtin_amdgcn_cosf(r1);
            sy[w] = __builtin_amdgcn_sinf(r2); cy[w] = __builtin_amdgcn_cosf(r2);
        }

        // qubit 0: merged RX*RY cross-lane SU(2) butterfly.
        // U = RY*RX: alpha = c2c1 + i s2s1, beta = s2c1 - i c2s1
        {
            float aR = cy[0] * cx[0], aI = sy[0] * sx[0];
            float bR = sy[0] * cx[0], bI = -(cy[0] * sx[0]);
            float A2 = psign * aI, B1 = psign * bR;
            v2f aRv = splat(aR), A2v = splat(A2), B1v = splat(B1), bIv = splat(bI);
            #pragma unroll
            for (int k = 0; k < 4; ++k) {
                v2f qr = pswap2(sr[k]), qi = pswap2(si[k]);
                v2f orr = sr[k], oii = si[k];
                v2f nr = vfma(aRv, orr, vfma(A2v, oii, vfma(B1v, qr, -(bIv * qi))));
                v2f ni = vfma(aRv, oii, vfma(-A2v, orr, vfma(B1v, qi, bIv * qr)));
                sr[k] = nr; si[k] = ni;
            }
        }
        // qubit 1 (local K=2), qubit 2 (K=1), qubit 3 (within-v2f)
        rx_local<2>(sr, si, sx[1], cx[1]);
        ry_local<2>(sr, si, sy[1], cy[1]);
        rx_local<1>(sr, si, sx[2], cx[2]);
        ry_local<1>(sr, si, sy[2], cy[2]);
        rx_1(sr, si, sx[3], cx[3]);
        ry_1(sr, si, sy[3], cy[3]);

        // CZ ring
        sr[0] = sr[0] * czA; si[0] = si[0] * czA;
        sr[1] = sr[1] * czB; si[1] = si[1] * czB;
        sr[2] = sr[2] * czC; si[2] = si[2] * czC;
        sr[3] = sr[3] * czD; si[3] = si[3] * czD;
    }

    // ---- measurement ----
    v2f pz[4];
    #pragma unroll
    for (int k = 0; k < 4; ++k) pz[k] = vfma(sr[k], sr[k], si[k] * si[k]);
    float e0 = pz[0].x + pz[0].y, e1 = pz[1].x + pz[1].y;
    float e2 = pz[2].x + pz[2].y, e3 = pz[3].x + pz[3].y;
    float o0 = pz[0].x - pz[0].y, o1 = pz[1].x - pz[1].y;
    float o2 = pz[2].x - pz[2].y, o3 = pz[3].x - pz[3].y;
    float q0l = -psign * (e0 + e1 + e2 + e3);     // qubit0 sign = bit3 = p
    float q1l = (e0 + e1) - (e2 + e3);            // local bit2
    float q2l = (e0 - e1) + (e2 - e3);            // local bit1
    float q3l = (o0 + o1) + (o2 + o3);            // local bit0
    float q0f = q0l + pswap(q0l);
    float q1f = q1l + pswap(q1l);
    float q2f = q2l + pswap(q2l);
    float q3f = q3l + pswap(q3l);

    // ---- head (duplicated on both lanes; uniform s_load weights) ----
    float oacc = b4[0];
    #pragma unroll
    for (int j = 0; j < 8; ++j) {
        float g = b3[j];
        g = fmaf(q0f, W3[j],      g);
        g = fmaf(q1f, W3[8 + j],  g);
        g = fmaf(q2f, W3[16 + j], g);
        g = fmaf(q3f, W3[24 + j], g);
        oacc = fmaf(tanh_fast(g), W4[j], oacc);
    }
    if (p == 0) out[t] = oacc;
}

extern "C" void kernel_launch(void* const* d_in, const int* in_sizes, int n_in,
                              void* d_out, int out_size, void* d_ws, size_t ws_size,
                              hipStream_t stream) {
    const float* xy = (const float*)d_in[0];
    const float* W1 = (const float*)d_in[1];
    const float* b1 = (const float*)d_in[2];
    const float* W2 = (const float*)d_in[3];
    const float* b2 = (const float*)d_in[4];
    const float* W3 = (const float*)d_in[5];
    const float* b3 = (const float*)d_in[6];
    const float* W4 = (const float*)d_in[7];
    const float* b4 = (const float*)d_in[8];
    float* out = (float*)d_out;

    const int B = in_sizes[0] / 2;
    const int threads = 2 * B;
    const int block = 256;
    const int grid = (threads + block - 1) / block;
    qpinn_kernel<<<grid, block, 0, stream>>>(xy, W1, b1, W2, b2, W3, b3, W4, b4, out, B);
}

// Round 4
// 17.333 us; speedup vs baseline: 1.1418x; 1.1418x over previous
//
#include <hip/hip_runtime.h>

typedef float v2f __attribute__((ext_vector_type(2)));

__device__ __forceinline__ v2f vfma(v2f a, v2f b, v2f c) {
    return __builtin_elementwise_fma(a, b, c);
}
__device__ __forceinline__ v2f splat(float x) { v2f r; r.x = x; r.y = x; return r; }

__device__ __forceinline__ float rcp_fast(float x) { return __builtin_amdgcn_rcpf(x); }

// tanh(x) = (1 - e^{-2x}) / (1 + e^{-2x}); all inputs here bounded |x| < ~6.
__device__ __forceinline__ float tanh_fast(float x) {
    float e = __expf(-2.0f * x);
    return (1.0f - e) * rcp_fast(1.0f + e);
}

__device__ __forceinline__ void cmul(float ar, float ai, float br, float bi,
                                     float& cr, float& ci) {
    cr = ar * br - ai * bi;
    ci = ar * bi + ai * br;
}

// ---- packed butterfly gates ----
// State: 16 complex amps packed by index: sr[k] = (Re psi[2k], Re psi[2k+1]), si likewise.
// Qubit w has stride R = 8>>w. For R>=2 the butterfly pairs v2f index k with k+K, K=R/2.
template<int K>
__device__ __forceinline__ void rx_gate_p(v2f (&sr)[8], v2f (&si)[8], float s, float c) {
    v2f cs = splat(c), ss = splat(s);
    #pragma unroll
    for (int k = 0; k < 8; ++k) {
        if ((k & K) == 0) {
            const int e = k + K;
            v2f ar = sr[k], ai = si[k], br = sr[e], bi = si[e];
            sr[k] = vfma(cs, ar,  ss * bi);
            si[k] = vfma(cs, ai, -(ss * br));
            sr[e] = vfma(cs, br,  ss * ai);
            si[e] = vfma(cs, bi, -(ss * ar));
        }
    }
}
template<int K>
__device__ __forceinline__ void ry_gate_p(v2f (&sr)[8], v2f (&si)[8], float s, float c) {
    v2f cs = splat(c), ss = splat(s);
    #pragma unroll
    for (int k = 0; k < 8; ++k) {
        if ((k & K) == 0) {
            const int e = k + K;
            v2f ar = sr[k], ai = si[k], br = sr[e], bi = si[e];
            sr[k] = vfma(cs, ar, -(ss * br));
            si[k] = vfma(cs, ai, -(ss * bi));
            sr[e] = vfma(ss, ar,  cs * br);
            si[e] = vfma(ss, ai,  cs * bi);
        }
    }
}
// Qubit 3 (R=1): pairs live inside one v2f -> .yx swizzle (op_sel), per-lane signs.
__device__ __forceinline__ void rx_gate_1(v2f (&sr)[8], v2f (&si)[8], float s, float c) {
    v2f cs = splat(c), ss = splat(s);
    #pragma unroll
    for (int k = 0; k < 8; ++k) {
        v2f r = sr[k], i = si[k];
        sr[k] = vfma(cs, r,  ss * i.yx);
        si[k] = vfma(cs, i, -(ss * r.yx));
    }
}
__device__ __forceinline__ void ry_gate_1(v2f (&sr)[8], v2f (&si)[8], float s, float c) {
    v2f cs = splat(c);
    v2f sn; sn.x = -s; sn.y = s;
    #pragma unroll
    for (int k = 0; k < 8; ++k) {
        v2f r = sr[k], i = si[k];
        sr[k] = vfma(cs, r, sn * r.yx);
        si[k] = vfma(cs, i, sn * i.yx);
    }
}

__global__ void __launch_bounds__(256)
qpinn_kernel(const float* __restrict__ xy,
             const float* __restrict__ W1, const float* __restrict__ b1,
             const float* __restrict__ W2, const float* __restrict__ b2,
             const float* __restrict__ W3, const float* __restrict__ b3,
             const float* __restrict__ W4, const float* __restrict__ b4,
             float* __restrict__ out, int B)
{
    // UNIFORM control flow throughout (no early return): weight loads with
    // compile-time offsets are then provably uniform -> SMEM s_load on the
    // scalar pipe (no VALU/VMEM cost). Tail handled by clamping (duplicate
    // threads recompute the same element and write the same value).
    int tid = blockIdx.x * blockDim.x + threadIdx.x;
    int t = tid < B ? tid : B - 1;

    float2 P = reinterpret_cast<const float2*>(xy)[t];
    float x = P.x, y = P.y;

    // ---- front MLP: h = tanh(xy @ W1 + b1), W1 (2,16) row-major ----
    float h[16];
    #pragma unroll
    for (int j = 0; j < 16; ++j)
        h[j] = tanh_fast(fmaf(x, W1[j], fmaf(y, W1[16 + j], b1[j])));

    // ---- initial state: tensor power. psi[d] = u0^(4-k) u1^k, k = popcount(d) ----
    // u0 = (cos a - sin a)/sqrt2 * e^{-ib}, u1 = (cos a + sin a)/sqrt2 * e^{+ib},
    // a = x*pi/2, b = y*pi/2. Raw v_sin/v_cos take revolutions: rev = x/4.
    float sa = __builtin_amdgcn_sinf(0.25f * x), ca = __builtin_amdgcn_cosf(0.25f * x);
    float sb = __builtin_amdgcn_sinf(0.25f * y), cb = __builtin_amdgcn_cosf(0.25f * y);
    const float is2 = 0.70710678118654752f;
    float m0 = is2 * (ca - sa), m1 = is2 * (ca + sa);
    float u0r = m0 * cb, u0i = -m0 * sb;
    float u1r = m1 * cb, u1i =  m1 * sb;

    float p2r, p2i, p3r, p3i, p4r, p4i;
    float q2r, q2i, q3r, q3i, q4r, q4i;
    cmul(u0r, u0i, u0r, u0i, p2r, p2i);
    cmul(p2r, p2i, u0r, u0i, p3r, p3i);
    cmul(p3r, p3i, u0r, u0i, p4r, p4i);
    cmul(u1r, u1i, u1r, u1i, q2r, q2i);
    cmul(q2r, q2i, u1r, u1i, q3r, q3i);
    cmul(q3r, q3i, u1r, u1i, q4r, q4i);

    float trr[5], tii[5];
    trr[0] = p4r; tii[0] = p4i;
    cmul(p3r, p3i, u1r, u1i, trr[1], tii[1]);
    cmul(p2r, p2i, q2r, q2i, trr[2], tii[2]);
    cmul(u0r, u0i, q3r, q3i, trr[3], tii[3]);
    trr[4] = q4r; tii[4] = q4i;

    constexpr int pc[16] = {0,1,1,2, 1,2,2,3, 1,2,2,3, 2,3,3,4};
    v2f sr[8], si[8];
    #pragma unroll
    for (int k = 0; k < 8; ++k) {
        sr[k].x = trr[pc[2*k]];   sr[k].y = trr[pc[2*k+1]];
        si[k].x = tii[pc[2*k]];   si[k].y = tii[pc[2*k+1]];
    }

    const float REV = 0.5f * 0.15915494309189535f; // (t/2) in revolutions per unit t

    // ---- layers ----
    #pragma unroll
    for (int l = 0; l < 5; ++l) {
        // angles: a8[m] = tanh(h @ W2[:, l*8+m] + b2[l*8+m]); W2 (16,40) row-major.
        float a8[8];
        #pragma unroll
        for (int m2 = 0; m2 < 4; ++m2) {
            const int j = l * 8 + 2 * m2;
            v2f acc; acc.x = b2[j]; acc.y = b2[j + 1];
            #pragma unroll
            for (int k = 0; k < 16; ++k) {
                v2f w; w.x = W2[k * 40 + j]; w.y = W2[k * 40 + j + 1];
                acc = vfma(splat(h[k]), w, acc);
            }
            a8[2*m2]     = tanh_fast(acc.x);
            a8[2*m2 + 1] = tanh_fast(acc.y);
        }

        float s, c, rev;
        // qubit 0 (K=4)
        rev = a8[0] * REV; s = __builtin_amdgcn_sinf(rev); c = __builtin_amdgcn_cosf(rev);
        rx_gate_p<4>(sr, si, s, c);
        rev = a8[4] * REV; s = __builtin_amdgcn_sinf(rev); c = __builtin_amdgcn_cosf(rev);
        ry_gate_p<4>(sr, si, s, c);
        // qubit 1 (K=2)
        rev = a8[1] * REV; s = __builtin_amdgcn_sinf(rev); c = __builtin_amdgcn_cosf(rev);
        rx_gate_p<2>(sr, si, s, c);
        rev = a8[5] * REV; s = __builtin_amdgcn_sinf(rev); c = __builtin_amdgcn_cosf(rev);
        ry_gate_p<2>(sr, si, s, c);
        // qubit 2 (K=1)
        rev = a8[2] * REV; s = __builtin_amdgcn_sinf(rev); c = __builtin_amdgcn_cosf(rev);
        rx_gate_p<1>(sr, si, s, c);
        rev = a8[6] * REV; s = __builtin_amdgcn_sinf(rev); c = __builtin_amdgcn_cosf(rev);
        ry_gate_p<1>(sr, si, s, c);
        // qubit 3 (within-v2f)
        rev = a8[3] * REV; s = __builtin_amdgcn_sinf(rev); c = __builtin_amdgcn_cosf(rev);
        rx_gate_1(sr, si, s, c);
        rev = a8[7] * REV; s = __builtin_amdgcn_sinf(rev); c = __builtin_amdgcn_cosf(rev);
        ry_gate_1(sr, si, s, c);

        // CZ ring: sign -1 at basis states {3,6,9,12}
        sr[1].y = -sr[1].y;  si[1].y = -si[1].y;   // state 3
        sr[3].x = -sr[3].x;  si[3].x = -si[3].x;   // state 6
        sr[4].y = -sr[4].y;  si[4].y = -si[4].y;   // state 9
        sr[6].x = -sr[6].x;  si[6].x = -si[6].x;   // state 12
    }

    // ---- measurement ----
    float ev[8], ov[8];
    #pragma unroll
    for (int k = 0; k < 8; ++k) {
        v2f pz = vfma(sr[k], sr[k], si[k] * si[k]);
        ev[k] = pz.x + pz.y;   // both lanes same sign for qubits 0-2
        ov[k] = pz.x - pz.y;   // lane sign split for qubit 3
    }
    float q0 = 0.f, q1 = 0.f, q2 = 0.f, q3 = 0.f;
    #pragma unroll
    for (int k = 0; k < 8; ++k) {
        q0 += (k & 4) ? -ev[k] : ev[k];
        q1 += (k & 2) ? -ev[k] : ev[k];
        q2 += (k & 1) ? -ev[k] : ev[k];
        q3 += ov[k];
    }

    // ---- head: out = tanh(q @ W3 + b3) @ W4 + b4 ; W3 (4,8) row-major ----
    float oacc = b4[0];
    #pragma unroll
    for (int j2 = 0; j2 < 4; ++j2) {
        const int j = 2 * j2;
        v2f g;  g.x = b3[j];  g.y = b3[j + 1];
        v2f w;
        w.x = W3[j];      w.y = W3[j + 1];       g = vfma(splat(q0), w, g);
        w.x = W3[8 + j];  w.y = W3[8 + j + 1];   g = vfma(splat(q1), w, g);
        w.x = W3[16 + j]; w.y = W3[16 + j + 1];  g = vfma(splat(q2), w, g);
        w.x = W3[24 + j]; w.y = W3[24 + j + 1];  g = vfma(splat(q3), w, g);
        oacc = fmaf(tanh_fast(g.x), W4[j],     oacc);
        oacc = fmaf(tanh_fast(g.y), W4[j + 1], oacc);
    }
    out[t] = oacc;
}

extern "C" void kernel_launch(void* const* d_in, const int* in_sizes, int n_in,
                              void* d_out, int out_size, void* d_ws, size_t ws_size,
                              hipStream_t stream) {
    const float* xy = (const float*)d_in[0];
    const float* W1 = (const float*)d_in[1];
    const float* b1 = (const float*)d_in[2];
    const float* W2 = (const float*)d_in[3];
    const float* b2 = (const float*)d_in[4];
    const float* W3 = (const float*)d_in[5];
    const float* b3 = (const float*)d_in[6];
    const float* W4 = (const float*)d_in[7];
    const float* b4 = (const float*)d_in[8];
    float* out = (float*)d_out;

    const int B = in_sizes[0] / 2;
    const int block = 256;
    const int grid = (B + block - 1) / block;
    qpinn_kernel<<<grid, block, 0, stream>>>(xy, W1, b1, W2, b2, W3, b3, W4, b4, out, B);
}